// Round 11
// baseline (369.256 us; speedup 1.0000x reference)
//
#include <hip/hip_runtime.h>
#include <hip/hip_fp16.h>
#include <math.h>

#define N_NODES 50000
#define N_EDGES 600000
#define N_GRAPHS 64
#define DFEAT 128
#define H3 384
#define OUTD 10
#define SCAN_BLOCKS 196    // 196*256 = 50176 >= 50000
#define FILL_BLOCKS 2344   // 2344*256 = 600064 >= 600000
#define POOL_CHUNKS 16     // blocks per graph in pooling
#define APAD 136           // fp16 LDS row pad: 272B stride -> conflict-free b128 reads
#define ZTAIL (N_GRAPHS * H3 + N_GRAPHS)   // pooled floats + cnt ints to zero = 24640

typedef _Float16 f16x8 __attribute__((ext_vector_type(8)));
typedef float f32x4 __attribute__((ext_vector_type(4)));
typedef float f32x2 __attribute__((ext_vector_type(2)));

// ---------------- degree histogram (in-degree at dst) + per-edge rank ----------------
__global__ __launch_bounds__(256) void k_deg(const int* __restrict__ ei, int* __restrict__ deg,
                                             int* __restrict__ rank) {
    int e = blockIdx.x * 256 + threadIdx.x;
    if (e >= N_EDGES) return;
    int dst = ei[N_EDGES + e];
    rank[e] = atomicAdd(&deg[dst], 1);
}

// ---------------- stage 1: per-block partial sums ----------------
__global__ __launch_bounds__(256) void k_part(const int* __restrict__ deg, int* __restrict__ part) {
    __shared__ int red[256];
    int tid = threadIdx.x;
    int i = blockIdx.x * 256 + tid;
    red[tid] = (i < N_NODES) ? deg[i] : 0;
    __syncthreads();
    for (int s = 128; s > 0; s >>= 1) {
        if (tid < s) red[tid] += red[tid + s];
        __syncthreads();
    }
    if (tid == 0) part[blockIdx.x] = red[0];
}

// ---------------- stage 2+3 merged: each block redundantly scans the 196 partials
// (784B, one LDS scan) for its exclusive base, then does the block-local scan -> offs.
__global__ __launch_bounds__(256) void k_offsets(const int* __restrict__ deg, const int* __restrict__ part,
                                                 int* __restrict__ offs, float* __restrict__ dinv) {
    __shared__ int pbuf[256];
    __shared__ int buf[256];
    int tid = threadIdx.x;
    int pv = (tid < SCAN_BLOCKS) ? part[tid] : 0;
    pbuf[tid] = pv;
    __syncthreads();
    for (int d = 1; d < 256; d <<= 1) {
        int t = (tid >= d) ? pbuf[tid - d] : 0;
        __syncthreads();
        pbuf[tid] += t;
        __syncthreads();
    }
    int base = (blockIdx.x > 0) ? pbuf[blockIdx.x - 1] : 0;  // exclusive base (broadcast read)
    int i = blockIdx.x * 256 + tid;
    int v = (i < N_NODES) ? deg[i] : 0;
    buf[tid] = v;
    __syncthreads();
    for (int d = 1; d < 256; d <<= 1) {
        int t = (tid >= d) ? buf[tid - d] : 0;
        __syncthreads();
        buf[tid] += t;
        __syncthreads();
    }
    if (i < N_NODES) {
        int excl = base + buf[tid] - v;
        offs[i] = excl;
        dinv[i] = rsqrtf((float)v + 1.0f);
        if (i == N_NODES - 1) offs[N_NODES] = base + buf[tid];  // total == N_EDGES
    }
}

// ---------------- fill CSR buckets + weight transpose + pooled/cnt zero (merged) --------
__global__ __launch_bounds__(256) void k_fill_prep(const int* __restrict__ ei, const int* __restrict__ offs,
                                                   const int* __restrict__ rank, const float* __restrict__ dinv,
                                                   unsigned int* __restrict__ epack,
                                                   const float* __restrict__ W1, const float* __restrict__ W2,
                                                   const float* __restrict__ W3, _Float16* __restrict__ Wt,
                                                   float* __restrict__ pooled, int* __restrict__ cnt) {
    int b = blockIdx.x;
    if (b < FILL_BLOCKS) {
        int e = b * 256 + threadIdx.x;
        if (e >= N_EDGES) return;
        int s = ei[e];
        int t = ei[N_EDGES + e];
        unsigned short dh = __half_as_ushort(__float2half(dinv[s]));
        epack[offs[t] + rank[e]] = (unsigned int)s | ((unsigned int)dh << 16);  // s < 50000 < 2^16
    } else if (b < FILL_BLOCKS + 192) {
        int idx = (b - FILL_BLOCKS) * 256 + threadIdx.x;   // 0..49151
        int l = idx >> 14, r = idx & 16383;
        const float* W = (l == 0) ? W1 : (l == 1) ? W2 : W3;
        int k = r >> 7, n = r & 127;
        Wt[l * 16384 + n * 128 + k] = (_Float16)W[k * 128 + n];
    } else {
        int idx = (b - FILL_BLOCKS - 192) * 256 + threadIdx.x;
        if (idx < N_GRAPHS * H3) pooled[idx] = 0.0f;
        else if (idx < ZTAIL) cnt[idx - N_GRAPHS * H3] = 0;
    }
}

// ---------------- T[Mx128](fp8 e4m3) = A[Mx128] @ W (via fp16 MFMA) ----------------
// A fragments direct global->registers (consumed once); Ws stays in LDS (4x reuse).
template <bool A_FP16>
__global__ __launch_bounds__(256) void gemm_mfma(const void* __restrict__ Aptr, const _Float16* __restrict__ Wt,
                                                 unsigned char* __restrict__ T, int M) {
    __shared__ _Float16 Ws[128 * APAD];   // 34.8 KB
    int tid = threadIdx.x;
    int base = blockIdx.x * 64;
    for (int c = tid; c < 2048; c += 256) {
        int n = c >> 4, c8 = (c & 15) << 3;
        *(f16x8*)&Ws[n * APAD + c8] = *(const f16x8*)&Wt[n * 128 + c8];
    }
    int wave = tid >> 6, lane = tid & 63;
    int m = lane & 15, quad = lane >> 4;
    int gr = base + wave * 16 + m;
    int grc = (gr < M) ? gr : (M - 1);
    f16x8 areg[4];
    if (A_FP16) {
        const _Float16* A = (const _Float16*)Aptr;
#pragma unroll
        for (int kc = 0; kc < 4; ++kc)
            areg[kc] = *(const f16x8*)&A[(size_t)grc * 128 + kc * 32 + quad * 8];
    } else {
        const float* A = (const float*)Aptr;
#pragma unroll
        for (int kc = 0; kc < 4; ++kc) {
            const float* src = A + (size_t)grc * 128 + kc * 32 + quad * 8;
            float4 v0 = *(const float4*)(src);
            float4 v1 = *(const float4*)(src + 4);
            f16x8 h;
            h[0] = (_Float16)v0.x; h[1] = (_Float16)v0.y; h[2] = (_Float16)v0.z; h[3] = (_Float16)v0.w;
            h[4] = (_Float16)v1.x; h[5] = (_Float16)v1.y; h[6] = (_Float16)v1.z; h[7] = (_Float16)v1.w;
            areg[kc] = h;
        }
    }
    __syncthreads();
    f32x4 acc[8];
#pragma unroll
    for (int ct = 0; ct < 8; ++ct) acc[ct] = (f32x4){0.f, 0.f, 0.f, 0.f};
#pragma unroll
    for (int kc = 0; kc < 4; ++kc) {
#pragma unroll
        for (int ct = 0; ct < 8; ++ct) {
            f16x8 b = *(const f16x8*)&Ws[(ct * 16 + m) * APAD + kc * 32 + quad * 8];
            acc[ct] = __builtin_amdgcn_mfma_f32_16x16x32_f16(b, areg[kc], acc[ct], 0, 0, 0);
        }
    }
    if (gr < M) {
#pragma unroll
        for (int ct = 0; ct < 8; ++ct) {
            int col = ct * 16 + quad * 4;
            int p = __builtin_amdgcn_cvt_pk_fp8_f32(acc[ct][0], acc[ct][1], 0, false);
            p     = __builtin_amdgcn_cvt_pk_fp8_f32(acc[ct][2], acc[ct][3], p, true);
            *(int*)(T + (size_t)gr * 128 + col) = p;  // 4B-aligned
        }
    }
}

// ---------------- per-node gather-accumulate (r4 measured-best, unchanged) ----------------
__global__ __launch_bounds__(256) void gather_agg(const unsigned int* __restrict__ T32,
                                                  const unsigned int* __restrict__ epack,
                                                  const int* __restrict__ offs,
                                                  const float* __restrict__ dinv, const float* __restrict__ bias,
                                                  __half2* __restrict__ H2) {
    int h = threadIdx.x >> 5;        // half-wave 0..7
    int l32 = threadIdx.x & 31;      // dims 4*l32 .. 4*l32+3
    int node = blockIdx.x * 8 + h;   // grid = 6250, exact
    unsigned su = T32[(size_t)node * 32 + l32];
    float di = dinv[node];
    float4 b4 = *(const float4*)(bias + l32 * 4);
    float a0 = 0.f, a1 = 0.f, a2 = 0.f, a3 = 0.f;
    int lo = offs[node], hi = offs[node + 1];
    int hm1 = hi - 1;
    for (int e0 = lo; e0 < hi; e0 += 16) {
        unsigned p[16];
#pragma unroll
        for (int j = 0; j < 16; ++j) p[j] = epack[min(e0 + j, hm1)];
        unsigned u[16];
#pragma unroll
        for (int j = 0; j < 16; ++j) u[j] = T32[(size_t)(p[j] & 0xffffu) * 32 + l32];
#pragma unroll
        for (int j = 0; j < 16; ++j) {
            float c = (e0 + j < hi) ? __half2float(__ushort_as_half((unsigned short)(p[j] >> 16))) : 0.0f;
            f32x2 tl = __builtin_amdgcn_cvt_pk_f32_fp8(u[j], false);
            f32x2 th = __builtin_amdgcn_cvt_pk_f32_fp8(u[j], true);
            a0 += tl.x * c; a1 += tl.y * c; a2 += th.x * c; a3 += th.y * c;
        }
    }
    f32x2 sl = __builtin_amdgcn_cvt_pk_f32_fp8(su, false), sh = __builtin_amdgcn_cvt_pk_f32_fp8(su, true);
    float dd = di * di;
    float r0 = di * a0 + sl.x * dd + b4.x;
    float r1 = di * a1 + sl.y * dd + b4.y;
    float r2 = di * a2 + sh.x * dd + b4.z;
    float r3 = di * a3 + sh.y * dd + b4.w;
    H2[(size_t)node * 64 + l32 * 2]     = __floats2half2_rn(r0, r1);
    H2[(size_t)node * 64 + l32 * 2 + 1] = __floats2half2_rn(r2, r3);
}

// ---------------- pooling + fused MLP head (last-block-done pattern, replay-idempotent) ----
// grid = 64 graphs x 16 chunks. Each chunk accumulates its slice of all 3 layers into
// pooled via device atomics, then threadfence + counter increment. The LAST chunk of
// each graph runs that graph's MLP + log_softmax inline. No spin, no co-residency
// assumption -> hang-proof. The last chunk also RESETS cnt[g] and pooled[g] so the
// kernel is idempotent under any harness replay that skips the prep kernels.
__global__ __launch_bounds__(256) void pool_mlp(const __half2* __restrict__ H0,
                                                const __half2* __restrict__ H1,
                                                const __half2* __restrict__ H2buf,
                                                const int* __restrict__ batch,
                                                float* __restrict__ pooled, int* __restrict__ cnt,
                                                const float* __restrict__ l1W, const float* __restrict__ l1b,
                                                const float* __restrict__ l2W, const float* __restrict__ l2b,
                                                float* __restrict__ out) {
    __shared__ int bounds[2];
    __shared__ float2 red[256];
    __shared__ int lastFlag;
    __shared__ float p[H3];
    __shared__ float hid[H3];
    __shared__ float o10[OUTD];
    int g = blockIdx.x >> 4;        // / POOL_CHUNKS
    int chunk = blockIdx.x & (POOL_CHUNKS - 1);
    int tid = threadIdx.x;
    int d2 = tid & 63, sub = tid >> 6;  // 4 row-accumulators
    if (tid < 2) {
        int target = g + tid;  // lower_bound(batch, target)
        int lo = 0, hi = N_NODES;
        while (lo < hi) {
            int mid = (lo + hi) >> 1;
            if (batch[mid] < target) lo = mid + 1; else hi = mid;
        }
        bounds[tid] = lo;
    }
    __syncthreads();
    int lo = bounds[0], hi = bounds[1];
    int n = hi - lo;
    int per = (n + POOL_CHUNKS - 1) / POOL_CHUNKS;
    int s = lo + chunk * per;
    int e = s + per; if (e > hi) e = hi;
    const __half2* Hs[3] = {H0, H1, H2buf};
    for (int l = 0; l < 3; ++l) {
        const __half2* H = Hs[l];
        float ax = 0.0f, ay = 0.0f;
        for (int r = s + sub; r < e; r += 4) {
            float2 v = __half22float2(H[(size_t)r * 64 + d2]);
            ax += v.x; ay += v.y;
        }
        red[tid] = make_float2(ax, ay);
        __syncthreads();
        if (sub == 0 && s < e) {
            float2 v0 = red[d2], v1 = red[64 + d2], v2 = red[128 + d2], v3 = red[192 + d2];
            atomicAdd(&pooled[g * H3 + l * 128 + d2 * 2],     v0.x + v1.x + v2.x + v3.x);
            atomicAdd(&pooled[g * H3 + l * 128 + d2 * 2 + 1], v0.y + v1.y + v2.y + v3.y);
        }
        __syncthreads();
    }
    // completion: last chunk of this graph runs the MLP
    __threadfence();
    if (tid == 0) {
        int old = atomicAdd(&cnt[g], 1);
        lastFlag = (old == POOL_CHUNKS - 1);
        if (lastFlag) cnt[g] = 0;   // self-clean: next launch/replay starts at 0
    }
    __syncthreads();
    if (!lastFlag) return;
    __threadfence();   // acquire: make other chunks' pooled atomics visible to our loads
    float inv = 1.0f / fmaxf((float)n, 1.0f);
    for (int k = tid; k < H3; k += 256) p[k] = pooled[g * H3 + k] * inv;
    __syncthreads();
    for (int k = tid; k < H3; k += 256) pooled[g * H3 + k] = 0.0f;  // self-clean accumulator
    for (int j = tid; j < H3; j += 256) {
        float acc = l1b[j];
        for (int k = 0; k < H3; ++k) acc += p[k] * l1W[k * H3 + j];
        hid[j] = fmaxf(acc, 0.0f);
    }
    __syncthreads();
    if (tid < OUTD) {
        float o = l2b[tid];
        for (int k = 0; k < H3; ++k) o += hid[k] * l2W[k * OUTD + tid];
        o10[tid] = o;
        out[g * OUTD + tid] = o;
    }
    __syncthreads();
    if (tid == 0) {
        float m = o10[0];
        for (int j = 1; j < OUTD; ++j) m = fmaxf(m, o10[j]);
        float sum = 0.0f;
        for (int j = 0; j < OUTD; ++j) sum += expf(o10[j] - m);
        float lse = m + logf(sum);
        for (int j = 0; j < OUTD; ++j) out[N_GRAPHS * OUTD + g * OUTD + j] = o10[j] - lse;
    }
}

extern "C" void kernel_launch(void* const* d_in, const int* in_sizes, int n_in,
                              void* d_out, int out_size, void* d_ws, size_t ws_size,
                              hipStream_t stream) {
    const float* x      = (const float*)d_in[0];
    const float* W1     = (const float*)d_in[1];
    const float* b1     = (const float*)d_in[2];
    const float* W2     = (const float*)d_in[3];
    const float* b2     = (const float*)d_in[4];
    const float* W3     = (const float*)d_in[5];
    const float* b3     = (const float*)d_in[6];
    const float* lin1_W = (const float*)d_in[7];
    const float* lin1_b = (const float*)d_in[8];
    const float* lin2_W = (const float*)d_in[9];
    const float* lin2_b = (const float*)d_in[10];
    const int* edge_index = (const int*)d_in[11];
    const int* batch      = (const int*)d_in[12];

    char* ws = (char*)d_ws;
    auto alloc = [&](size_t bytes) -> void* {
        void* p = (void*)ws;
        ws += (bytes + 255) & ~(size_t)255;
        return p;
    };
    int*   deg    = (int*)  alloc((size_t)N_NODES * 4);
    int*   part   = (int*)  alloc((size_t)SCAN_BLOCKS * 4);
    int*   offs   = (int*)  alloc((size_t)(N_NODES + 1) * 4);
    int*   rank   = (int*)  alloc((size_t)N_EDGES * 4);
    float* dinv   = (float*)alloc((size_t)N_NODES * 4);
    unsigned int* epack = (unsigned int*)alloc((size_t)N_EDGES * 4);
    unsigned char* T = (unsigned char*)alloc((size_t)N_NODES * 128);
    __half* Hbuf[3];
    for (int l = 0; l < 3; ++l) Hbuf[l] = (__half*)alloc((size_t)N_NODES * 128 * 2);
    _Float16* Wt  = (_Float16*)alloc((size_t)3 * 128 * 128 * 2);
    float* pooled = (float*)alloc((size_t)N_GRAPHS * H3 * 4);
    int*   cnt    = (int*)  alloc((size_t)N_GRAPHS * 4);

    hipMemsetAsync(deg, 0, (size_t)N_NODES * 4, stream);
    k_deg<<<(N_EDGES + 255) / 256, 256, 0, stream>>>(edge_index, deg, rank);
    k_part<<<SCAN_BLOCKS, 256, 0, stream>>>(deg, part);
    k_offsets<<<SCAN_BLOCKS, 256, 0, stream>>>(deg, part, offs, dinv);
    k_fill_prep<<<FILL_BLOCKS + 192 + 97, 256, 0, stream>>>(edge_index, offs, rank, dinv, epack,
                                                            W1, W2, W3, Wt, pooled, cnt);

    const float* bs[3] = {b1, b2, b3};
    for (int l = 0; l < 3; ++l) {
        if (l == 0)
            gemm_mfma<false><<<(N_NODES + 63) / 64, 256, 0, stream>>>(x, Wt, T, N_NODES);
        else
            gemm_mfma<true><<<(N_NODES + 63) / 64, 256, 0, stream>>>(Hbuf[l - 1], Wt + (size_t)l * 16384, T, N_NODES);
        gather_agg<<<N_NODES / 8, 256, 0, stream>>>((const unsigned int*)T, epack, offs, dinv, bs[l], (__half2*)Hbuf[l]);
    }
    pool_mlp<<<N_GRAPHS * POOL_CHUNKS, 256, 0, stream>>>((const __half2*)Hbuf[0], (const __half2*)Hbuf[1],
                                                         (const __half2*)Hbuf[2], batch, pooled, cnt,
                                                         lin1_W, lin1_b, lin2_W, lin2_b, (float*)d_out);
}

// Round 12
// 271.803 us; speedup vs baseline: 1.3585x; 1.3585x over previous
//
#include <hip/hip_runtime.h>
#include <hip/hip_fp16.h>
#include <math.h>

#define N_NODES 50000
#define N_EDGES 600000
#define N_GRAPHS 64
#define DFEAT 128
#define H3 384
#define OUTD 10
#define SCAN_BLOCKS 196    // 196*256 = 50176 >= 50000
#define FILL_BLOCKS 2344   // 2344*256 = 600064 >= 600000
#define POOL_CHUNKS 16     // blocks per graph in pooling
#define APAD 136           // fp16 LDS row pad: 272B stride -> conflict-free b128 reads

typedef _Float16 f16x8 __attribute__((ext_vector_type(8)));
typedef float f32x4 __attribute__((ext_vector_type(4)));
typedef float f32x2 __attribute__((ext_vector_type(2)));

// ---------------- degree histogram (in-degree at dst) + per-edge rank ----------------
__global__ __launch_bounds__(256) void k_deg(const int* __restrict__ ei, int* __restrict__ deg,
                                             int* __restrict__ rank) {
    int e = blockIdx.x * 256 + threadIdx.x;
    if (e >= N_EDGES) return;
    int dst = ei[N_EDGES + e];
    rank[e] = atomicAdd(&deg[dst], 1);
}

// ---------------- stage 1: per-block partial sums ----------------
__global__ __launch_bounds__(256) void k_part(const int* __restrict__ deg, int* __restrict__ part) {
    __shared__ int red[256];
    int tid = threadIdx.x;
    int i = blockIdx.x * 256 + tid;
    red[tid] = (i < N_NODES) ? deg[i] : 0;
    __syncthreads();
    for (int s = 128; s > 0; s >>= 1) {
        if (tid < s) red[tid] += red[tid + s];
        __syncthreads();
    }
    if (tid == 0) part[blockIdx.x] = red[0];
}

// ---------------- stage 2+3 merged: each block redundantly scans the 196 partials
// (784B, one LDS scan) for its exclusive base, then does the block-local scan -> offs.
__global__ __launch_bounds__(256) void k_offsets(const int* __restrict__ deg, const int* __restrict__ part,
                                                 int* __restrict__ offs, float* __restrict__ dinv) {
    __shared__ int pbuf[256];
    __shared__ int buf[256];
    int tid = threadIdx.x;
    int pv = (tid < SCAN_BLOCKS) ? part[tid] : 0;
    pbuf[tid] = pv;
    __syncthreads();
    for (int d = 1; d < 256; d <<= 1) {
        int t = (tid >= d) ? pbuf[tid - d] : 0;
        __syncthreads();
        pbuf[tid] += t;
        __syncthreads();
    }
    int base = (blockIdx.x > 0) ? pbuf[blockIdx.x - 1] : 0;  // exclusive base (broadcast read)
    int i = blockIdx.x * 256 + tid;
    int v = (i < N_NODES) ? deg[i] : 0;
    buf[tid] = v;
    __syncthreads();
    for (int d = 1; d < 256; d <<= 1) {
        int t = (tid >= d) ? buf[tid - d] : 0;
        __syncthreads();
        buf[tid] += t;
        __syncthreads();
    }
    if (i < N_NODES) {
        int excl = base + buf[tid] - v;
        offs[i] = excl;
        dinv[i] = rsqrtf((float)v + 1.0f);
        if (i == N_NODES - 1) offs[N_NODES] = base + buf[tid];  // total == N_EDGES
    }
}

// ---------------- fill CSR buckets + weight transpose + pooled zero (merged) ----------------
__global__ __launch_bounds__(256) void k_fill_prep(const int* __restrict__ ei, const int* __restrict__ offs,
                                                   const int* __restrict__ rank, const float* __restrict__ dinv,
                                                   unsigned int* __restrict__ epack,
                                                   const float* __restrict__ W1, const float* __restrict__ W2,
                                                   const float* __restrict__ W3, _Float16* __restrict__ Wt,
                                                   float* __restrict__ pooled) {
    int b = blockIdx.x;
    if (b < FILL_BLOCKS) {
        int e = b * 256 + threadIdx.x;
        if (e >= N_EDGES) return;
        int s = ei[e];
        int t = ei[N_EDGES + e];
        unsigned short dh = __half_as_ushort(__float2half(dinv[s]));
        epack[offs[t] + rank[e]] = (unsigned int)s | ((unsigned int)dh << 16);  // s < 50000 < 2^16
    } else if (b < FILL_BLOCKS + 192) {
        int idx = (b - FILL_BLOCKS) * 256 + threadIdx.x;   // 0..49151
        int l = idx >> 14, r = idx & 16383;
        const float* W = (l == 0) ? W1 : (l == 1) ? W2 : W3;
        int k = r >> 7, n = r & 127;
        Wt[l * 16384 + n * 128 + k] = (_Float16)W[k * 128 + n];
    } else {
        int idx = (b - FILL_BLOCKS - 192) * 256 + threadIdx.x;
        if (idx < N_GRAPHS * H3) pooled[idx] = 0.0f;
    }
}

// ---------------- T[Mx128](fp8 e4m3) = A[Mx128] @ W (via fp16 MFMA) ----------------
// A fragments direct global->registers (consumed once); Ws stays in LDS (4x reuse).
template <bool A_FP16>
__global__ __launch_bounds__(256) void gemm_mfma(const void* __restrict__ Aptr, const _Float16* __restrict__ Wt,
                                                 unsigned char* __restrict__ T, int M) {
    __shared__ _Float16 Ws[128 * APAD];   // 34.8 KB
    int tid = threadIdx.x;
    int base = blockIdx.x * 64;
    for (int c = tid; c < 2048; c += 256) {
        int n = c >> 4, c8 = (c & 15) << 3;
        *(f16x8*)&Ws[n * APAD + c8] = *(const f16x8*)&Wt[n * 128 + c8];
    }
    int wave = tid >> 6, lane = tid & 63;
    int m = lane & 15, quad = lane >> 4;
    int gr = base + wave * 16 + m;
    int grc = (gr < M) ? gr : (M - 1);
    f16x8 areg[4];
    if (A_FP16) {
        const _Float16* A = (const _Float16*)Aptr;
#pragma unroll
        for (int kc = 0; kc < 4; ++kc)
            areg[kc] = *(const f16x8*)&A[(size_t)grc * 128 + kc * 32 + quad * 8];
    } else {
        const float* A = (const float*)Aptr;
#pragma unroll
        for (int kc = 0; kc < 4; ++kc) {
            const float* src = A + (size_t)grc * 128 + kc * 32 + quad * 8;
            float4 v0 = *(const float4*)(src);
            float4 v1 = *(const float4*)(src + 4);
            f16x8 h;
            h[0] = (_Float16)v0.x; h[1] = (_Float16)v0.y; h[2] = (_Float16)v0.z; h[3] = (_Float16)v0.w;
            h[4] = (_Float16)v1.x; h[5] = (_Float16)v1.y; h[6] = (_Float16)v1.z; h[7] = (_Float16)v1.w;
            areg[kc] = h;
        }
    }
    __syncthreads();
    f32x4 acc[8];
#pragma unroll
    for (int ct = 0; ct < 8; ++ct) acc[ct] = (f32x4){0.f, 0.f, 0.f, 0.f};
#pragma unroll
    for (int kc = 0; kc < 4; ++kc) {
#pragma unroll
        for (int ct = 0; ct < 8; ++ct) {
            f16x8 b = *(const f16x8*)&Ws[(ct * 16 + m) * APAD + kc * 32 + quad * 8];
            acc[ct] = __builtin_amdgcn_mfma_f32_16x16x32_f16(b, areg[kc], acc[ct], 0, 0, 0);
        }
    }
    if (gr < M) {
#pragma unroll
        for (int ct = 0; ct < 8; ++ct) {
            int col = ct * 16 + quad * 4;
            int p = __builtin_amdgcn_cvt_pk_fp8_f32(acc[ct][0], acc[ct][1], 0, false);
            p     = __builtin_amdgcn_cvt_pk_fp8_f32(acc[ct][2], acc[ct][3], p, true);
            *(int*)(T + (size_t)gr * 128 + col) = p;  // 4B-aligned
        }
    }
}

// ---------------- per-node gather-accumulate: H(fp16) = Ahat * T(fp8) + b ----------------
// One node per 32-lane half-wave: lane loads a uint = 4 fp8 dims, 32 lanes = full 128B row.
// 8 nodes per 256-thread block (grid 6250 exact).
// Single 16-deep PREDICATED batch per iteration (index clamped to hi-1, coefficient
// zeroed for out-of-range edges): deg<=16 (~90% of nodes) costs exactly one epack-wait
// + one T-row-wait -- no serial scalar tail. Self-row + bias loads hoisted pre-loop.
__global__ __launch_bounds__(256) void gather_agg(const unsigned int* __restrict__ T32,
                                                  const unsigned int* __restrict__ epack,
                                                  const int* __restrict__ offs,
                                                  const float* __restrict__ dinv, const float* __restrict__ bias,
                                                  __half2* __restrict__ H2) {
    int h = threadIdx.x >> 5;        // half-wave 0..7
    int l32 = threadIdx.x & 31;      // dims 4*l32 .. 4*l32+3
    int node = blockIdx.x * 8 + h;   // grid = 6250, exact
    unsigned su = T32[(size_t)node * 32 + l32];
    float di = dinv[node];
    float4 b4 = *(const float4*)(bias + l32 * 4);
    float a0 = 0.f, a1 = 0.f, a2 = 0.f, a3 = 0.f;
    int lo = offs[node], hi = offs[node + 1];
    int hm1 = hi - 1;
    for (int e0 = lo; e0 < hi; e0 += 16) {
        unsigned p[16];
#pragma unroll
        for (int j = 0; j < 16; ++j) p[j] = epack[min(e0 + j, hm1)];
        unsigned u[16];
#pragma unroll
        for (int j = 0; j < 16; ++j) u[j] = T32[(size_t)(p[j] & 0xffffu) * 32 + l32];
#pragma unroll
        for (int j = 0; j < 16; ++j) {
            float c = (e0 + j < hi) ? __half2float(__ushort_as_half((unsigned short)(p[j] >> 16))) : 0.0f;
            f32x2 tl = __builtin_amdgcn_cvt_pk_f32_fp8(u[j], false);
            f32x2 th = __builtin_amdgcn_cvt_pk_f32_fp8(u[j], true);
            a0 += tl.x * c; a1 += tl.y * c; a2 += th.x * c; a3 += th.y * c;
        }
    }
    f32x2 sl = __builtin_amdgcn_cvt_pk_f32_fp8(su, false), sh = __builtin_amdgcn_cvt_pk_f32_fp8(su, true);
    float dd = di * di;
    float r0 = di * a0 + sl.x * dd + b4.x;
    float r1 = di * a1 + sl.y * dd + b4.y;
    float r2 = di * a2 + sh.x * dd + b4.z;
    float r3 = di * a3 + sh.y * dd + b4.w;
    H2[(size_t)node * 64 + l32 * 2]     = __floats2half2_rn(r0, r1);
    H2[(size_t)node * 64 + l32 * 2 + 1] = __floats2half2_rn(r2, r3);
}

// ---------------- segment-sum pooling, all 3 layers in one dispatch ----------------
__global__ __launch_bounds__(256) void pool_kernel(const __half2* __restrict__ H0,
                                                   const __half2* __restrict__ H1,
                                                   const __half2* __restrict__ H2buf,
                                                   const int* __restrict__ batch,
                                                   float* __restrict__ pooled) {
    __shared__ int bounds[2];
    __shared__ float2 red[256];
    int g = blockIdx.x >> 4;        // / POOL_CHUNKS
    int chunk = blockIdx.x & (POOL_CHUNKS - 1);
    int tid = threadIdx.x;
    int d2 = tid & 63, sub = tid >> 6;  // 4 row-accumulators
    if (tid < 2) {
        int target = g + tid;  // lower_bound(batch, target)
        int lo = 0, hi = N_NODES;
        while (lo < hi) {
            int mid = (lo + hi) >> 1;
            if (batch[mid] < target) lo = mid + 1; else hi = mid;
        }
        bounds[tid] = lo;
    }
    __syncthreads();
    int lo = bounds[0], hi = bounds[1];
    int n = hi - lo;
    int per = (n + POOL_CHUNKS - 1) / POOL_CHUNKS;
    int s = lo + chunk * per;
    int e = s + per; if (e > hi) e = hi;
    const __half2* Hs[3] = {H0, H1, H2buf};
    for (int l = 0; l < 3; ++l) {
        const __half2* H = Hs[l];
        float ax = 0.0f, ay = 0.0f;
        for (int r = s + sub; r < e; r += 4) {
            float2 v = __half22float2(H[(size_t)r * 64 + d2]);
            ax += v.x; ay += v.y;
        }
        red[tid] = make_float2(ax, ay);
        __syncthreads();
        if (sub == 0 && s < e) {
            float2 v0 = red[d2], v1 = red[64 + d2], v2 = red[128 + d2], v3 = red[192 + d2];
            atomicAdd(&pooled[g * H3 + l * 128 + d2 * 2],     v0.x + v1.x + v2.x + v3.x);
            atomicAdd(&pooled[g * H3 + l * 128 + d2 * 2 + 1], v0.y + v1.y + v2.y + v3.y);
        }
        __syncthreads();
    }
}

// ---------------- MLP head + log_softmax, one block per graph ----------------
__global__ __launch_bounds__(384) void mlp_kernel(const float* __restrict__ pooled,
                                                  const int* __restrict__ batch,
                                                  const float* __restrict__ l1W, const float* __restrict__ l1b,
                                                  const float* __restrict__ l2W, const float* __restrict__ l2b,
                                                  float* __restrict__ out) {
    __shared__ float p[H3];
    __shared__ float hid[H3];
    __shared__ float o10[OUTD];
    __shared__ int bnd[2];
    int g = blockIdx.x, tid = threadIdx.x;
    if (tid < 2) {
        int target = g + tid;  // lower_bound(batch, target)
        int lo = 0, hi = N_NODES;
        while (lo < hi) {
            int mid = (lo + hi) >> 1;
            if (batch[mid] < target) lo = mid + 1; else hi = mid;
        }
        bnd[tid] = lo;
    }
    __syncthreads();
    float inv = 1.0f / fmaxf((float)(bnd[1] - bnd[0]), 1.0f);
    p[tid] = pooled[g * H3 + tid] * inv;
    __syncthreads();
    float acc = l1b[tid];
    for (int k = 0; k < H3; ++k) acc += p[k] * l1W[k * H3 + tid];
    hid[tid] = fmaxf(acc, 0.0f);
    __syncthreads();
    if (tid < OUTD) {
        float o = l2b[tid];
        for (int k = 0; k < H3; ++k) o += hid[k] * l2W[k * OUTD + tid];
        o10[tid] = o;
        out[g * OUTD + tid] = o;
    }
    __syncthreads();
    if (tid == 0) {
        float m = o10[0];
        for (int j = 1; j < OUTD; ++j) m = fmaxf(m, o10[j]);
        float s = 0.0f;
        for (int j = 0; j < OUTD; ++j) s += expf(o10[j] - m);
        float lse = m + logf(s);
        for (int j = 0; j < OUTD; ++j) out[N_GRAPHS * OUTD + g * OUTD + j] = o10[j] - lse;
    }
}

extern "C" void kernel_launch(void* const* d_in, const int* in_sizes, int n_in,
                              void* d_out, int out_size, void* d_ws, size_t ws_size,
                              hipStream_t stream) {
    const float* x      = (const float*)d_in[0];
    const float* W1     = (const float*)d_in[1];
    const float* b1     = (const float*)d_in[2];
    const float* W2     = (const float*)d_in[3];
    const float* b2     = (const float*)d_in[4];
    const float* W3     = (const float*)d_in[5];
    const float* b3     = (const float*)d_in[6];
    const float* lin1_W = (const float*)d_in[7];
    const float* lin1_b = (const float*)d_in[8];
    const float* lin2_W = (const float*)d_in[9];
    const float* lin2_b = (const float*)d_in[10];
    const int* edge_index = (const int*)d_in[11];
    const int* batch      = (const int*)d_in[12];

    char* ws = (char*)d_ws;
    auto alloc = [&](size_t bytes) -> void* {
        void* p = (void*)ws;
        ws += (bytes + 255) & ~(size_t)255;
        return p;
    };
    int*   deg    = (int*)  alloc((size_t)N_NODES * 4);
    int*   part   = (int*)  alloc((size_t)SCAN_BLOCKS * 4);
    int*   offs   = (int*)  alloc((size_t)(N_NODES + 1) * 4);
    int*   rank   = (int*)  alloc((size_t)N_EDGES * 4);
    float* dinv   = (float*)alloc((size_t)N_NODES * 4);
    unsigned int* epack = (unsigned int*)alloc((size_t)N_EDGES * 4);
    unsigned char* T = (unsigned char*)alloc((size_t)N_NODES * 128);
    __half* Hbuf[3];
    for (int l = 0; l < 3; ++l) Hbuf[l] = (__half*)alloc((size_t)N_NODES * 128 * 2);
    _Float16* Wt  = (_Float16*)alloc((size_t)3 * 128 * 128 * 2);
    float* pooled = (float*)alloc((size_t)N_GRAPHS * H3 * 4);

    hipMemsetAsync(deg, 0, (size_t)N_NODES * 4, stream);
    k_deg<<<(N_EDGES + 255) / 256, 256, 0, stream>>>(edge_index, deg, rank);
    k_part<<<SCAN_BLOCKS, 256, 0, stream>>>(deg, part);
    k_offsets<<<SCAN_BLOCKS, 256, 0, stream>>>(deg, part, offs, dinv);
    k_fill_prep<<<FILL_BLOCKS + 192 + 96, 256, 0, stream>>>(edge_index, offs, rank, dinv, epack,
                                                            W1, W2, W3, Wt, pooled);

    const float* bs[3] = {b1, b2, b3};
    for (int l = 0; l < 3; ++l) {
        if (l == 0)
            gemm_mfma<false><<<(N_NODES + 63) / 64, 256, 0, stream>>>(x, Wt, T, N_NODES);
        else
            gemm_mfma<true><<<(N_NODES + 63) / 64, 256, 0, stream>>>(Hbuf[l - 1], Wt + (size_t)l * 16384, T, N_NODES);
        gather_agg<<<N_NODES / 8, 256, 0, stream>>>((const unsigned int*)T, epack, offs, dinv, bs[l], (__half2*)Hbuf[l]);
    }
    pool_kernel<<<N_GRAPHS * POOL_CHUNKS, 256, 0, stream>>>((const __half2*)Hbuf[0], (const __half2*)Hbuf[1],
                                                            (const __half2*)Hbuf[2], batch, pooled);
    mlp_kernel<<<N_GRAPHS, 384, 0, stream>>>(pooled, batch, lin1_W, lin1_b, lin2_W, lin2_b, (float*)d_out);
}